// Round 1
// baseline (443.164 us; speedup 1.0000x reference)
//
#include <hip/hip_runtime.h>
#include <math.h>

// Problem constants (from reference)
#define NPTS   65536        // 256*256
#define NB     5            // batch of x
#define NX     25
#define NY     7
#define NZ     6
#define NW     5
#define FG     (NB*NX*NY*NZ*NW)   // 26250 f_grid elements
// out layout: [0]=loss, [1 .. 65536]=theta[0], [65537 ..]=grid_new

// Kernel A: s[n] = sum_i x[n,i]*theta[i] (n=0..4), ws[5] = sum |theta|,
// and copy theta -> out_theta.
__global__ void reduce_kernel(const float* __restrict__ x,
                              const float* __restrict__ theta,
                              float* __restrict__ out_theta,
                              float* __restrict__ ws) {
    __shared__ float smem[4 * 6];   // 4 waves x 6 partials
    int idx = blockIdx.x * blockDim.x + threadIdx.x;   // 0..65535 (grid=256x256)
    float t = theta[idx];
    out_theta[idx] = t;

    float vals[6];
#pragma unroll
    for (int n = 0; n < 5; ++n) vals[n] = x[n * NPTS + idx] * t;
    vals[5] = fabsf(t);

    int lane = threadIdx.x & 63;
    int wave = threadIdx.x >> 6;
#pragma unroll
    for (int k = 0; k < 6; ++k) {
        float v = vals[k];
#pragma unroll
        for (int off = 32; off > 0; off >>= 1) v += __shfl_down(v, off, 64);
        if (lane == 0) smem[wave * 6 + k] = v;
    }
    __syncthreads();
    if (threadIdx.x < 6) {
        float acc = smem[threadIdx.x] + smem[6 + threadIdx.x] +
                    smem[12 + threadIdx.x] + smem[18 + threadIdx.x];
        atomicAdd(&ws[threadIdx.x], acc);
    }
}

// Kernel B: compute f_grid (26250 elems), write into out grid slot j,
// reduce loss = sum(f_grid * W4) - 0.5 * sum|theta|.
__global__ void fgrid_kernel(const float* __restrict__ ws,
                             const int* __restrict__ jptr,
                             float* __restrict__ out) {
    __shared__ float red[256];
    const int tid = threadIdx.x;

    float s[5];
#pragma unroll
    for (int n = 0; n < 5; ++n) s[n] = ws[n];
    const float abs_sum = ws[5];
    const int j = *jptr;

    float* grid_out = out + 1 + NPTS + (size_t)j * FG;

    const float PI2 = 6.283185307179586f;
    const float dx = PI2 / 24.0f;   // x step
    const float dy = 0.03f;         // 0.18/6
    const float dz = 0.036f;        // 0.18/5
    const float dw = 0.05f;         // 0.2/4

    float local = 0.0f;
    for (int e = tid; e < FG; e += blockDim.x) {
        int d = e % NW;
        int c = (e / NW) % NZ;
        int b = (e / (NW * NZ)) % NY;
        int a = (e / (NW * NZ * NY)) % NX;
        int n = e / (NW * NZ * NY * NX);

        float xv = PI2 * (float)a / 24.0f;
        float cv = cosf(xv);
        float yv = -0.09f + dy * (float)b;
        float zv = -0.09f + dz * (float)c;
        float wv = 0.9f + dw * (float)d;

        float arg = s[n] * cv * wv + yv + zv;
        float f = expf(-arg * arg);
        grid_out[e] = f;

        float w4 = dx * ((a == 0 || a == NX - 1) ? 0.5f : 1.0f)
                 * dy * ((b == 0 || b == NY - 1) ? 0.5f : 1.0f)
                 * dz * ((c == 0 || c == NZ - 1) ? 0.5f : 1.0f)
                 * dw * ((d == 0 || d == NW - 1) ? 0.5f : 1.0f);
        local += f * w4;
    }

    red[tid] = local;
    __syncthreads();
    for (int stride = 128; stride > 0; stride >>= 1) {
        if (tid < stride) red[tid] += red[tid + stride];
        __syncthreads();
    }
    if (tid == 0) out[0] = red[0] - 0.5f * abs_sum;
}

extern "C" void kernel_launch(void* const* d_in, const int* in_sizes, int n_in,
                              void* d_out, int out_size, void* d_ws, size_t ws_size,
                              hipStream_t stream) {
    const float* x     = (const float*)d_in[0];   // [5,256,256]
    const float* theta = (const float*)d_in[1];   // [1,256,256]
    const float* grid  = (const float*)d_in[2];   // [2000,5,25,7,6,5]
    const int*   jptr  = (const int*)d_in[3];     // scalar

    float* out = (float*)d_out;
    float* ws  = (float*)d_ws;                    // ws[0..4]=s, ws[5]=abs_sum

    // zero the reduction scratch (ws is poisoned 0xAA each launch)
    hipMemsetAsync(ws, 0, 6 * sizeof(float), stream);

    // Kernel A: projections + |theta| sum + theta passthrough
    reduce_kernel<<<NPTS / 256, 256, 0, stream>>>(x, theta, out + 1, ws);

    // Bulk copy of grid input -> grid output (slot j overwritten next).
    const size_t grid_elems = (size_t)in_sizes[2];
    hipMemcpyAsync(out + 1 + NPTS, grid, grid_elems * sizeof(float),
                   hipMemcpyDeviceToDevice, stream);

    // Kernel B: f_grid into slot j + loss finalize
    fgrid_kernel<<<1, 256, 0, stream>>>(ws, jptr, out);
}

// Round 2
// 362.411 us; speedup vs baseline: 1.2228x; 1.2228x over previous
//
#include <hip/hip_runtime.h>
#include <math.h>

// Problem constants (from reference)
#define NPTS   65536        // 256*256
#define NB     5            // batch of x
#define NX     25
#define NY     7
#define NZ     6
#define NW     5
#define FG     (NB*NX*NY*NZ*NW)       // 26250 f_grid elements
#define GRID_ELEMS (2000 * FG)        // 52,500,000
#define NCHUNK (GRID_ELEMS / 4)       // 13,125,000 float4 chunks (exact)
// out layout: [0]=loss, [1 .. 65536]=theta[0], [65537 ..]=grid_new
// ws layout: [0..4]=s[n], [5]=sum|theta|, [6]=sum(f*W4)

// float4 with only 4-byte alignment guarantee (dst out+65537 is 4 mod 16)
typedef float float4a __attribute__((ext_vector_type(4), aligned(4)));

// Kernel A: s[n] = sum_i x[n,i]*theta[i] (n=0..4), ws[5] = sum |theta|,
// and copy theta -> out_theta.
__global__ void reduce_kernel(const float* __restrict__ x,
                              const float* __restrict__ theta,
                              float* __restrict__ out_theta,
                              float* __restrict__ ws) {
    __shared__ float smem[4 * 6];   // 4 waves x 6 partials
    int idx = blockIdx.x * blockDim.x + threadIdx.x;   // 0..65535
    float t = theta[idx];
    out_theta[idx] = t;

    float vals[6];
#pragma unroll
    for (int n = 0; n < 5; ++n) vals[n] = x[n * NPTS + idx] * t;
    vals[5] = fabsf(t);

    int lane = threadIdx.x & 63;
    int wave = threadIdx.x >> 6;
#pragma unroll
    for (int k = 0; k < 6; ++k) {
        float v = vals[k];
#pragma unroll
        for (int off = 32; off > 0; off >>= 1) v += __shfl_down(v, off, 64);
        if (lane == 0) smem[wave * 6 + k] = v;
    }
    __syncthreads();
    if (threadIdx.x < 6) {
        float acc = smem[threadIdx.x] + smem[6 + threadIdx.x] +
                    smem[12 + threadIdx.x] + smem[18 + threadIdx.x];
        atomicAdd(&ws[threadIdx.x], acc);
    }
}

// Kernel B (fused): float4 grid-stride copy grid->out_grid; chunks that
// overlap slot j compute f_grid instead and accumulate loss into ws[6].
__global__ void __launch_bounds__(256)
copy_fgrid_kernel(const float* __restrict__ grid,
                  float* __restrict__ out_grid,      // out + 1 + NPTS
                  const float* __restrict__ ws_in,
                  float* __restrict__ ws_out,
                  const int* __restrict__ jptr) {
    const int j = *jptr;
    const long long jlo = (long long)j * FG;
    const long long jhi = jlo + FG;

    float s[5];
#pragma unroll
    for (int n = 0; n < 5; ++n) s[n] = ws_in[n];

    const float PI2 = 6.283185307179586f;
    const float dx = PI2 / 24.0f;
    const float dy = 0.03f;         // 0.18/6
    const float dz = 0.036f;        // 0.18/5
    const float dw = 0.05f;         // 0.2/4

    float local = 0.0f;
    const long long stride = (long long)gridDim.x * blockDim.x;
    for (long long c = (long long)blockIdx.x * blockDim.x + threadIdx.x;
         c < NCHUNK; c += stride) {
        const long long base = c * 4;
        float4a v = *(const float4a*)(grid + base);   // src 16B-aligned
        if (base + 3 >= jlo && base < jhi) {
            // rare path: some of the 4 elems lie in slot j -> compute f
#pragma unroll
            for (int q = 0; q < 4; ++q) {
                long long e = base + q;
                if (e >= jlo && e < jhi) {
                    int e2 = (int)(e - jlo);
                    int d  = e2 % NW;
                    int cz = (e2 / NW) % NZ;
                    int b  = (e2 / (NW * NZ)) % NY;
                    int a  = (e2 / (NW * NZ * NY)) % NX;
                    int n  = e2 / (NW * NZ * NY * NX);

                    float xv = PI2 * (float)a / 24.0f;
                    float cv = cosf(xv);
                    float yv = -0.09f + dy * (float)b;
                    float zv = -0.09f + dz * (float)cz;
                    float wv = 0.9f + dw * (float)d;

                    float arg = s[n] * cv * wv + yv + zv;
                    float f = expf(-arg * arg);
                    v[q] = f;

                    float w4 = dx * ((a == 0 || a == NX - 1) ? 0.5f : 1.0f)
                             * dy * ((b == 0 || b == NY - 1) ? 0.5f : 1.0f)
                             * dz * ((cz == 0 || cz == NZ - 1) ? 0.5f : 1.0f)
                             * dw * ((d == 0 || d == NW - 1) ? 0.5f : 1.0f);
                    local += f * w4;
                }
            }
        }
        *(float4a*)(out_grid + base) = v;             // dst 4B-aligned
    }

    // wave-level reduction of loss contributions, one atomic per wave
#pragma unroll
    for (int off = 32; off > 0; off >>= 1) local += __shfl_down(local, off, 64);
    if ((threadIdx.x & 63) == 0 && local != 0.0f) atomicAdd(&ws_out[6], local);
}

// Kernel C: finalize loss
__global__ void finalize_kernel(const float* __restrict__ ws,
                                float* __restrict__ out) {
    out[0] = ws[6] - 0.5f * ws[5];
}

extern "C" void kernel_launch(void* const* d_in, const int* in_sizes, int n_in,
                              void* d_out, int out_size, void* d_ws, size_t ws_size,
                              hipStream_t stream) {
    const float* x     = (const float*)d_in[0];   // [5,256,256]
    const float* theta = (const float*)d_in[1];   // [1,256,256]
    const float* grid  = (const float*)d_in[2];   // [2000,5,25,7,6,5]
    const int*   jptr  = (const int*)d_in[3];     // scalar

    float* out = (float*)d_out;
    float* ws  = (float*)d_ws;

    // zero reduction scratch (ws is poisoned 0xAA each launch)
    hipMemsetAsync(ws, 0, 7 * sizeof(float), stream);

    // K1: projections + |theta| sum + theta passthrough
    reduce_kernel<<<NPTS / 256, 256, 0, stream>>>(x, theta, out + 1, ws);

    // K2: fused copy + f_grid scatter + loss partial
    copy_fgrid_kernel<<<16384, 256, 0, stream>>>(grid, out + 1 + NPTS,
                                                 ws, ws, jptr);

    // K3: finalize loss
    finalize_kernel<<<1, 1, 0, stream>>>(ws, out);
}